// Round 13
// baseline (209.153 us; speedup 1.0000x reference)
//
#include <hip/hip_runtime.h>
#include <hip/hip_bf16.h>

// MHA forward. DIM=768, HEADS=12, HD=64, B=4, T=2048.
// All matmuls 1-term f16 MFMA. Flash is KEY-SPLIT x2 (no-max softmax => partials combine
// exactly): each block does 128 q x 1024 keys, V-frags direct global->reg, K 2-slot LDS dbuf
// (16KB -> 6 blocks/CU target). combine kernel: (O0+O1)/(l0+l1) with LDS transpose.
//   prep_all -> gemm_qkv -> flash_attn(x1536) -> combine(x1536) -> gemm_out

typedef short short8 __attribute__((ext_vector_type(8)));
typedef _Float16 half8 __attribute__((ext_vector_type(8)));
typedef _Float16 half2v __attribute__((ext_vector_type(2)));
typedef float f32x16 __attribute__((ext_vector_type(16)));
typedef unsigned int uint4v __attribute__((ext_vector_type(4)));
typedef unsigned short ushort8v __attribute__((ext_vector_type(8)));
typedef unsigned short ushort4v __attribute__((ext_vector_type(4)));
typedef unsigned short ushort;

__device__ __forceinline__ ushort f2h(float x) {
    _Float16 h = (_Float16)x;                      // RNE
    return __builtin_bit_cast(ushort, h);
}
__device__ __forceinline__ float h2f(ushort u) {
    return (float)__builtin_bit_cast(_Float16, u);
}
__device__ __forceinline__ unsigned pk2h(float lo, float hi) {   // packed f16 pair, RTZ
    return __builtin_bit_cast(unsigned, __builtin_amdgcn_cvt_pkrtz(lo, hi));
}
__device__ __forceinline__ float dot2acc(unsigned pair, float acc) {  // acc += lo + hi
    const half2v ones = {(_Float16)1.0f, (_Float16)1.0f};
    return __builtin_amdgcn_fdot2(__builtin_bit_cast(half2v, pair), ones, acc, false);
}
__device__ __forceinline__ short8 ldfrag(const ushort* buf, int row, int slotLogical) {
    int phys = slotLogical ^ (row & 7);
    return *reinterpret_cast<const short8*>(&buf[row * 64 + phys * 8]);
}
__device__ __forceinline__ f32x16 mfma16(half8 a, half8 b, f32x16 c) {
    return __builtin_amdgcn_mfma_f32_32x32x16_f16(a, b, c, 0, 0, 0);
}
__device__ __forceinline__ half8 ldfragh(const ushort* buf, int row, int slotLogical) {
    return __builtin_bit_cast(half8, ldfrag(buf, row, slotLogical));
}
__device__ __forceinline__ half8 ldh(const ushort* p) {
    return __builtin_bit_cast(half8, *reinterpret_cast<const short8*>(p));
}
__device__ __forceinline__ void gload16(const ushort* g, ushort* l) {
    __builtin_amdgcn_global_load_lds((__attribute__((address_space(1))) void*)g,
                                     (__attribute__((address_space(3))) void*)l, 16, 0, 0);
}

// ---------------- merged prep: cast x | permute+cast w_qkv | transpose+cast w_out ------------
__global__ __launch_bounds__(256) void prep_all(const float* __restrict__ x,
                                                const float* __restrict__ wqkv,
                                                const float* __restrict__ wout,
                                                ushort* __restrict__ Xh,
                                                ushort* __restrict__ Wt,
                                                ushort* __restrict__ Wo) {
    int b = blockIdx.x;
    if (b < 3072) {
        long i8 = (long)(b * 256 + threadIdx.x) * 8;
        float4 v0 = *reinterpret_cast<const float4*>(&x[i8]);
        float4 v1 = *reinterpret_cast<const float4*>(&x[i8 + 4]);
        float v[8] = {v0.x, v0.y, v0.z, v0.w, v1.x, v1.y, v1.z, v1.w};
        ushort8v hh;
#pragma unroll
        for (int j = 0; j < 8; ++j) hh[j] = f2h(v[j]);
        *reinterpret_cast<ushort8v*>(&Xh[i8]) = hh;
    } else if (b < 3072 + 864) {
        int id = (b - 3072) * 256 + threadIdx.x;  // 2304*96
        int n = id % 2304;
        int oct = id / 2304;
        int g = n >> 6, d = n & 63;
        int col = d * 36 + g;
        ushort8v hh;
#pragma unroll
        for (int i = 0; i < 8; ++i) hh[i] = f2h(wqkv[(long)(8 * oct + i) * 2304 + col]);
        *reinterpret_cast<ushort8v*>(&Wt[(long)n * 768 + 8 * oct]) = hh;
    } else {
        int id = (b - 3936) * 256 + threadIdx.x;  // 768*96
        int n = id % 768;
        int oct = id / 768;
        ushort8v hh;
#pragma unroll
        for (int i = 0; i < 8; ++i) hh[i] = f2h(wout[(long)(8 * oct + i) * 768 + n]);
        *reinterpret_cast<ushort8v*>(&Wo[(long)n * 768 + 8 * oct]) = hh;
    }
}

// ---------------- shared MFMA GEMM core (m97 structure, gload_lds w=16, swizzled src) --------
__device__ __forceinline__ void gemm_core(const ushort* __restrict__ A,
                                          const ushort* __restrict__ Bt,
                                          long aBase, long bBase,
                                          ushort* sA, ushort* sB, f32x16 (&acc)[2][2]) {
    const int tid = threadIdx.x;
    const int lane = tid & 63, w = tid >> 6;
    const int c31 = lane & 31, g1 = lane >> 5;
    const int wr = w >> 1, wc = w & 1;
    const int srow_in_chunk = lane >> 3;
    for (int k0 = 0; k0 < 768; k0 += 64) {
        __syncthreads();
#pragma unroll
        for (int t = 0; t < 4; ++t) {
            int row = w * 32 + t * 8 + srow_in_chunk;
            int sl = (lane & 7) ^ (row & 7);
            long goff = (long)row * 768 + k0 + sl * 8;
            int ldst = (w * 32 + t * 8) * 64;
            gload16(&A[aBase + goff], &sA[ldst]);
            gload16(&Bt[bBase + goff], &sB[ldst]);
        }
        __syncthreads();
#pragma unroll
        for (int ks = 0; ks < 4; ++ks) {
            half8 ah[2], bh[2];
#pragma unroll
            for (int i = 0; i < 2; ++i) {
                ah[i] = ldfragh(sA, wr * 64 + i * 32 + c31, 2 * ks + g1);
                bh[i] = ldfragh(sB, wc * 64 + i * 32 + c31, 2 * ks + g1);
            }
#pragma unroll
            for (int mi = 0; mi < 2; ++mi)
#pragma unroll
                for (int nj = 0; nj < 2; ++nj)
                    acc[mi][nj] = mfma16(ah[mi], bh[nj], acc[mi][nj]);
        }
    }
}

// ---------------- merged QKV projection -> Qf / Kf(scaled) / Vt(transposed) ----------------
__global__ __launch_bounds__(256) void gemm_qkv(const ushort* __restrict__ Xh,
                                                const ushort* __restrict__ Wt,
                                                ushort* __restrict__ Qf,
                                                ushort* __restrict__ Kf,
                                                ushort* __restrict__ Vt) {
    __shared__ ushort sA[128 * 64];
    __shared__ ushort sB[128 * 64];
    const int by0 = blockIdx.y * 128, bx0 = blockIdx.x * 128;
    f32x16 acc[2][2] = {};
    gemm_core(Xh, Wt, (long)by0 * 768, (long)bx0 * 768, sA, sB, acc);

    const int tid = threadIdx.x, lane = tid & 63, w = tid >> 6;
    const int c31 = lane & 31, g1 = lane >> 5;
    const int wr = w >> 1, wc = w & 1;
    const int bb = by0 >> 11, tb = by0 & 2047;
#pragma unroll
    for (int nj = 0; nj < 2; ++nj) {
        int n = bx0 + wc * 64 + nj * 32 + c31;
        int gg = n >> 6;
        int d = n & 63;
        if (gg < 24) {
            int kq = gg >= 12;
            int hh = gg - kq * 12;
            ushort* Dst = kq ? Kf : Qf;
            float sc = kq ? 0.1803368801111204f : 1.0f;   // K carries 0.125*log2(e)
            long cb = ((long)(bb * 12 + hh) * 2048) * 64 + d;
#pragma unroll
            for (int mi = 0; mi < 2; ++mi)
#pragma unroll
                for (int r = 0; r < 16; ++r) {
                    int t = tb + wr * 64 + mi * 32 + (r & 3) + 8 * (r >> 2) + 4 * g1;
                    Dst[cb + (long)t * 64] = f2h(acc[mi][nj][r] * sc);
                }
        } else {
            int hh = gg - 24;
            long vb = ((long)(bb * 12 + hh) * 64 + d) * 2048;
#pragma unroll
            for (int mi = 0; mi < 2; ++mi)
#pragma unroll
                for (int rq = 0; rq < 4; ++rq) {
                    int tq = tb + wr * 64 + mi * 32 + 8 * rq + 4 * g1;
                    ushort4v vv;
#pragma unroll
                    for (int j = 0; j < 4; ++j) vv[j] = f2h(acc[mi][nj][4 * rq + j]);
                    *reinterpret_cast<ushort4v*>(&Vt[vb + tq]) = vv;
                }
        }
    }
}

// ---------------- flash attention, key-split: 128 q x 1024 keys per block ----------------
// V-frags direct global->reg (same-iter use, unconditional); K 2-slot LDS dbuf (16KB).
// Outputs partial O^T (f16, [bh][d][q]) and l (f32) per key-half.
__global__ __launch_bounds__(256) void flash_attn(const ushort* __restrict__ Qf,
                                                  const ushort* __restrict__ Kf,
                                                  const ushort* __restrict__ Vt,
                                                  ushort* __restrict__ Op0,
                                                  ushort* __restrict__ Op1,
                                                  float* __restrict__ lp0,
                                                  float* __restrict__ lp1) {
    __shared__ ushort Ks[2][64 * 64];
    const int tid = threadIdx.x;
    const int w = tid >> 6;
    const int lane = tid & 63;
    const int c = lane & 31, g1 = lane >> 5;
    // swizzle: wgid&7 = bh&7 (XCD-local); inner: xblk(16) x kh(2); bh = (wgid&7)+8*(wgid>>8)
    const int wgid = blockIdx.x;
    const int inner = (wgid >> 3) & 31;
    const int xblk = inner >> 1;
    const int kh = inner & 1;
    const int bh = (wgid & 7) + 8 * (wgid >> 8);
    const int t0 = xblk * 128 + w * 32;
    const long hb = (long)bh * 2048 * 64;
    const int jbase = kh * 1024;

    // Q frags (scale folded into K)
    half8 qh[4];
    {
        const long qrow = hb + (long)(t0 + c) * 64;
#pragma unroll
        for (int ks = 0; ks < 4; ++ks)
            qh[ks] = ldh(&Qf[qrow + ks * 16 + g1 * 8]);
    }

    // K staging geometry (2 rows/thread, swizzled 16B slots)
    const int r0 = tid >> 3, sl = tid & 7, r1 = r0 + 32;
    const int off0 = r0 * 64 + ((sl ^ (r0 & 7)) * 8);
    const int off1 = r1 * 64 + ((sl ^ (r1 & 7)) * 8);

    {   // prologue: stage K tile 0
        short8 a = *reinterpret_cast<const short8*>(&Kf[hb + (long)(jbase + r0) * 64 + sl * 8]);
        short8 b = *reinterpret_cast<const short8*>(&Kf[hb + (long)(jbase + r1) * 64 + sl * 8]);
        *reinterpret_cast<short8*>(&Ks[0][off0]) = a;
        *reinterpret_cast<short8*>(&Ks[0][off1]) = b;
    }
    const ushort* kst0 = &Kf[hb + (long)(jbase + 64 + r0) * 64 + sl * 8];
    const ushort* kst1 = &Kf[hb + (long)(jbase + 64 + r1) * 64 + sl * 8];
    // V frag pointers: A-frag rows d=c / d=32+c, keys jbase + j*64 + ks*16 + g1*8
    const ushort* vp0 = &Vt[hb + (long)c * 2048 + jbase + g1 * 8];
    const ushort* vp1 = vp0 + 32 * 2048;
    __syncthreads();

    f32x16 o0 = {}, o1 = {};
    float lrun = 0.f;
    int cur = 0;

    for (int j = 0; j < 16; ++j) {
        // (a) V loads, first half (ks 0,1) — used this iter in PV (~400 cyc later)
        half8 vf0[4], vf1[4];
        vf0[0] = ldh(vp0);      vf1[0] = ldh(vp1);
        vf0[1] = ldh(vp0 + 16); vf1[1] = ldh(vp1 + 16);

        // (b) QK(j) from Ks[cur]
        f32x16 s0 = {}, s1 = {};
        __builtin_amdgcn_s_setprio(1);
#pragma unroll
        for (int ks = 0; ks < 4; ++ks) {
            int slot = 2 * ks + g1;
            half8 k0f = ldfragh(&Ks[cur][0], c, slot);
            half8 k1f = ldfragh(&Ks[cur][0], 32 + c, slot);
            s0 = mfma16(k0f, qh[ks], s0);
            s1 = mfma16(k1f, qh[ks], s1);
        }
        __builtin_amdgcn_s_setprio(0);

        // (c) V loads, second half; advance V pointers
        vf0[2] = ldh(vp0 + 32); vf1[2] = ldh(vp1 + 32);
        vf0[3] = ldh(vp0 + 48); vf1[3] = ldh(vp1 + 48);
        vp0 += 64; vp1 += 64;

        // (d) K(j+1) global loads
        short8 pk0, pk1;
        const bool nxt = j + 1 < 16;
        if (nxt) {
            pk0 = *reinterpret_cast<const short8*>(kst0);
            pk1 = *reinterpret_cast<const short8*>(kst1);
            kst0 += 4096; kst1 += 4096;
        }

        // (e) softmax: no-max exp2 (scale folded into K)
#pragma unroll
        for (int r = 0; r < 16; ++r) {
            s0[r] = exp2f(s0[r]);
            s1[r] = exp2f(s1[r]);
        }

        // (f) PV: P pack via cvt_pkrtz + permlane32_swap; l via fdot2; V from regs
        __builtin_amdgcn_s_setprio(1);
#pragma unroll
        for (int ks = 0; ks < 4; ++ks) {
            const int b8 = (ks & 1) * 8;
            uint4v dv;
#pragma unroll
            for (int mi = 0; mi < 2; ++mi) {
                float aLo = (ks < 2) ? s0[2 * mi + b8] : s1[2 * mi + b8];
                float aHi = (ks < 2) ? s0[2 * mi + b8 + 1] : s1[2 * mi + b8 + 1];
                float bLo = (ks < 2) ? s0[2 * mi + b8 + 4] : s1[2 * mi + b8 + 4];
                float bHi = (ks < 2) ? s0[2 * mi + b8 + 5] : s1[2 * mi + b8 + 5];
                unsigned xA = pk2h(aLo, aHi);
                unsigned xB = pk2h(bLo, bHi);
                lrun = dot2acc(xA, lrun);
                lrun = dot2acc(xB, lrun);
                auto rr = __builtin_amdgcn_permlane32_swap(xA, xB, false, false);
                dv[mi] = rr[0];
                dv[2 + mi] = rr[1];
            }
            half8 pb = __builtin_bit_cast(half8, dv);
            o0 = mfma16(vf0[ks], pb, o0);
            o1 = mfma16(vf1[ks], pb, o1);
        }
        __builtin_amdgcn_s_setprio(0);

        // (g) write K(j+1) into the other slot
        if (nxt) {
            *reinterpret_cast<short8*>(&Ks[cur ^ 1][off0]) = pk0;
            *reinterpret_cast<short8*>(&Ks[cur ^ 1][off1]) = pk1;
        }
        __syncthreads();
        cur ^= 1;
    }

    const float ltot = lrun + __shfl_xor(lrun, 32);
    // partial stores: Op[kh][(bh*64 + d)*2048 + q] f16 (coalesced along q), l f32
    ushort* Op = kh ? Op1 : Op0;
    float* lp = kh ? lp1 : lp0;
    const long pbase = ((long)bh * 64) * 2048 + t0 + c;
#pragma unroll
    for (int r = 0; r < 16; ++r) {
        int d0 = (r & 3) + 8 * (r >> 2) + 4 * g1;
        Op[pbase + (long)d0 * 2048] = f2h(o0[r]);
        Op[pbase + (long)(32 + d0) * 2048] = f2h(o1[r]);
    }
    if (g1 == 0) lp[(long)bh * 2048 + t0 + c] = ltot;
}

// ---------------- combine: Of[b][t][h*64+d] = (O0+O1)/(l0+l1), LDS 64x64 transpose ----------
__global__ __launch_bounds__(256) void combine(const ushort* __restrict__ Op0,
                                               const ushort* __restrict__ Op1,
                                               const float* __restrict__ lp0,
                                               const float* __restrict__ lp1,
                                               ushort* __restrict__ Of) {
    __shared__ float linv[64];
    __shared__ ushort tile[64][72];           // [t][d], padded
    const int bh = blockIdx.x >> 5;
    const int tb = blockIdx.x & 31;
    const int t0 = tb * 64;
    const int tid = threadIdx.x;
    if (tid < 64)
        linv[tid] = 1.0f / (lp0[(long)bh * 2048 + t0 + tid] + lp1[(long)bh * 2048 + t0 + tid]);
    __syncthreads();
#pragma unroll
    for (int it = 0; it < 2; ++it) {          // 512 tasks: (d 64) x (tg 8)
        int u = tid + 256 * it;
        int d = u & 63, tg = u >> 6;
        long base = ((long)bh * 64 + d) * 2048 + t0 + tg * 8;
        ushort8v a = *reinterpret_cast<const ushort8v*>(&Op0[base]);
        ushort8v b = *reinterpret_cast<const ushort8v*>(&Op1[base]);
#pragma unroll
        for (int j = 0; j < 8; ++j)
            tile[tg * 8 + j][d] = f2h((h2f(a[j]) + h2f(b[j])) * linv[tg * 8 + j]);
    }
    __syncthreads();
    const int bb = bh / 12, h = bh - bb * 12;
#pragma unroll
    for (int it = 0; it < 2; ++it) {          // 512 tasks: (t 64) x (dg 8)
        int u = tid + 256 * it;
        int dg = u & 7, t = u >> 3;
        ushort8v v;
#pragma unroll
        for (int j = 0; j < 8; ++j) v[j] = tile[t][dg * 8 + j];
        *reinterpret_cast<ushort8v*>(&Of[((long)(bb * 2048) + t0 + t) * 768 + h * 64 + dg * 8]) = v;
    }
}

// ---------------- out projection: 1-term f16 MFMA + bias, fp32 out ----------------
__global__ __launch_bounds__(256) void gemm_out(const ushort* __restrict__ Of,
                                                const ushort* __restrict__ Wo,
                                                const float* __restrict__ bias,
                                                float* __restrict__ Cout) {
    __shared__ ushort sA[128 * 64];
    __shared__ ushort sB[128 * 64];
    const int by0 = blockIdx.y * 128, bx0 = blockIdx.x * 128;
    f32x16 acc[2][2] = {};
    gemm_core(Of, Wo, (long)by0 * 768, (long)bx0 * 768, sA, sB, acc);

    const int tid = threadIdx.x, lane = tid & 63, w = tid >> 6;
    const int c31 = lane & 31, g1 = lane >> 5;
    const int wr = w >> 1, wc = w & 1;
#pragma unroll
    for (int nj = 0; nj < 2; ++nj) {
        int n = bx0 + wc * 64 + nj * 32 + c31;
        float bv = bias[n];
#pragma unroll
        for (int mi = 0; mi < 2; ++mi)
#pragma unroll
            for (int r = 0; r < 16; ++r) {
                int row = by0 + wr * 64 + mi * 32 + (r & 3) + 8 * (r >> 2) + 4 * g1;
                Cout[(long)row * 768 + n] = acc[mi][nj][r] + bv;
            }
    }
}

extern "C" void kernel_launch(void* const* d_in, const int* in_sizes, int n_in,
                              void* d_out, int out_size, void* d_ws, size_t ws_size,
                              hipStream_t stream) {
    const float* x     = (const float*)d_in[0];
    const float* w_qkv = (const float*)d_in[1];
    const float* w_out = (const float*)d_in[2];
    const float* b_out = (const float*)d_in[3];
    float* out = (float*)d_out;

    // ws layout (bytes); U = 48*2048*64*2 = 12,582,912 per f16 tensor
    const long U = 12582912;
    char* p = (char*)d_ws;
    ushort* Xh  = (ushort*)(p);                   // later: Of (combined flash output)
    ushort* Wt  = (ushort*)(p + U);               // 3,538,944 B
    ushort* Wo  = (ushort*)(p + U + 3538944);     // 1,179,648 B
    ushort* Qf  = (ushort*)(p + U + 4718592);
    ushort* Kf  = Qf + 6291456;
    ushort* Vt  = Kf + 6291456;
    ushort* Op0 = Vt + 6291456;
    ushort* Op1 = Op0 + 6291456;
    float*  lp0 = (float*)(Op1 + 6291456);        // 393,216 B each
    float*  lp1 = lp0 + 98304;
    ushort* Of  = Xh;

    prep_all  <<<4224, 256, 0, stream>>>(x, w_qkv, w_out, Xh, Wt, Wo);
    gemm_qkv  <<<dim3(18, 64), 256, 0, stream>>>(Xh, Wt, Qf, Kf, Vt);
    flash_attn<<<1536, 256, 0, stream>>>(Qf, Kf, Vt, Op0, Op1, lp0, lp1);
    combine   <<<1536, 256, 0, stream>>>(Op0, Op1, lp0, lp1, Of);
    gemm_out  <<<dim3(6, 64), 256, 0, stream>>>(Of, Wo, b_out, out);
}

// Round 14
// 205.457 us; speedup vs baseline: 1.0180x; 1.0180x over previous
//
#include <hip/hip_runtime.h>
#include <hip/hip_bf16.h>

// MHA forward. DIM=768, HEADS=12, HD=64, B=4, T=2048.
// All matmuls 1-term f16 MFMA (error budget ~2.3e-3 vs 5.9e-3 threshold):
//   prep_all -> gemm_qkv (256x128 tile, 512 thr, merged Q/K/V, V^T direct)
//   -> flash_attn (3-slot LDS rotation, T15 S-pipeline UNROLL-2 ping-pong, permlane pack,
//                  fdot2 l-sum, XCD swizzle)
//   -> gemm_out (256x128 tile, 512 thr, +bias)
// GEMM staging via global_load_lds w=16 with pre-swizzled source (linear LDS dest).

typedef short short8 __attribute__((ext_vector_type(8)));
typedef _Float16 half8 __attribute__((ext_vector_type(8)));
typedef _Float16 half2v __attribute__((ext_vector_type(2)));
typedef float f32x16 __attribute__((ext_vector_type(16)));
typedef unsigned int uint4v __attribute__((ext_vector_type(4)));
typedef unsigned short ushort8v __attribute__((ext_vector_type(8)));
typedef unsigned short ushort4v __attribute__((ext_vector_type(4)));
typedef unsigned short ushort;

__device__ __forceinline__ ushort f2h(float x) {
    _Float16 h = (_Float16)x;                      // RNE
    return __builtin_bit_cast(ushort, h);
}
__device__ __forceinline__ unsigned pk2h(float lo, float hi) {   // packed f16 pair, RTZ
    return __builtin_bit_cast(unsigned, __builtin_amdgcn_cvt_pkrtz(lo, hi));
}
__device__ __forceinline__ float dot2acc(unsigned pair, float acc) {  // acc += lo + hi
    const half2v ones = {(_Float16)1.0f, (_Float16)1.0f};
    return __builtin_amdgcn_fdot2(__builtin_bit_cast(half2v, pair), ones, acc, false);
}
__device__ __forceinline__ short8 ldfrag(const ushort* buf, int row, int slotLogical) {
    int phys = slotLogical ^ (row & 7);
    return *reinterpret_cast<const short8*>(&buf[row * 64 + phys * 8]);
}
__device__ __forceinline__ f32x16 mfma16(half8 a, half8 b, f32x16 c) {
    return __builtin_amdgcn_mfma_f32_32x32x16_f16(a, b, c, 0, 0, 0);
}
__device__ __forceinline__ half8 ldfragh(const ushort* buf, int row, int slotLogical) {
    return __builtin_bit_cast(half8, ldfrag(buf, row, slotLogical));
}
__device__ __forceinline__ void gload16(const ushort* g, ushort* l) {
    __builtin_amdgcn_global_load_lds((__attribute__((address_space(1))) void*)g,
                                     (__attribute__((address_space(3))) void*)l, 16, 0, 0);
}

// ---------------- merged prep: cast x | permute+cast w_qkv | transpose+cast w_out ------------
__global__ __launch_bounds__(256) void prep_all(const float* __restrict__ x,
                                                const float* __restrict__ wqkv,
                                                const float* __restrict__ wout,
                                                ushort* __restrict__ Xh,
                                                ushort* __restrict__ Wt,
                                                ushort* __restrict__ Wo) {
    int b = blockIdx.x;
    if (b < 3072) {
        long i8 = (long)(b * 256 + threadIdx.x) * 8;
        float4 v0 = *reinterpret_cast<const float4*>(&x[i8]);
        float4 v1 = *reinterpret_cast<const float4*>(&x[i8 + 4]);
        float v[8] = {v0.x, v0.y, v0.z, v0.w, v1.x, v1.y, v1.z, v1.w};
        ushort8v hh;
#pragma unroll
        for (int j = 0; j < 8; ++j) hh[j] = f2h(v[j]);
        *reinterpret_cast<ushort8v*>(&Xh[i8]) = hh;
    } else if (b < 3072 + 864) {
        int id = (b - 3072) * 256 + threadIdx.x;  // 2304*96
        int n = id % 2304;
        int oct = id / 2304;
        int g = n >> 6, d = n & 63;
        int col = d * 36 + g;
        ushort8v hh;
#pragma unroll
        for (int i = 0; i < 8; ++i) hh[i] = f2h(wqkv[(long)(8 * oct + i) * 2304 + col]);
        *reinterpret_cast<ushort8v*>(&Wt[(long)n * 768 + 8 * oct]) = hh;
    } else {
        int id = (b - 3936) * 256 + threadIdx.x;  // 768*96
        int n = id % 768;
        int oct = id / 768;
        ushort8v hh;
#pragma unroll
        for (int i = 0; i < 8; ++i) hh[i] = f2h(wout[(long)(8 * oct + i) * 768 + n]);
        *reinterpret_cast<ushort8v*>(&Wo[(long)n * 768 + 8 * oct]) = hh;
    }
}

// ---------------- MFMA GEMM core, 512 threads: C[256][128] = A[256][768] . Bt[128][768]^T ----
// 8 waves as 4M x 2N, each wave a 64x64 sub-tile (acc[2][2]). LDS: A 32KB + B 16KB.
// Staged via global_load_lds w=16: linear LDS dest, pre-swizzled global source (rule 21).
__device__ __forceinline__ void gemm_core(const ushort* __restrict__ A,
                                          const ushort* __restrict__ Bt,
                                          long aBase, long bBase,
                                          ushort* sA, ushort* sB, f32x16 (&acc)[2][2]) {
    const int tid = threadIdx.x;
    const int lane = tid & 63, w = tid >> 6;       // w 0..7
    const int c31 = lane & 31, g1 = lane >> 5;
    const int wr = w >> 1, wc = w & 1;             // wr 0..3 (M), wc 0..1 (N)
    const int rch = lane >> 3;                     // 0..7
    for (int k0 = 0; k0 < 768; k0 += 64) {
        __syncthreads();
#pragma unroll
        for (int t = 0; t < 4; ++t) {              // A: 256 rows x 64k
            int row = w * 32 + t * 8 + rch;
            int sl = (lane & 7) ^ (row & 7);
            gload16(&A[aBase + (long)row * 768 + k0 + sl * 8], &sA[(w * 32 + t * 8) * 64]);
        }
#pragma unroll
        for (int t = 0; t < 2; ++t) {              // B: 128 rows x 64k
            int row = w * 16 + t * 8 + rch;
            int sl = (lane & 7) ^ (row & 7);
            gload16(&Bt[bBase + (long)row * 768 + k0 + sl * 8], &sB[(w * 16 + t * 8) * 64]);
        }
        __syncthreads();
#pragma unroll
        for (int ks = 0; ks < 4; ++ks) {
            half8 ah[2], bh[2];
#pragma unroll
            for (int i = 0; i < 2; ++i) {
                ah[i] = ldfragh(sA, wr * 64 + i * 32 + c31, 2 * ks + g1);
                bh[i] = ldfragh(sB, wc * 64 + i * 32 + c31, 2 * ks + g1);
            }
#pragma unroll
            for (int mi = 0; mi < 2; ++mi)
#pragma unroll
                for (int nj = 0; nj < 2; ++nj)
                    acc[mi][nj] = mfma16(ah[mi], bh[nj], acc[mi][nj]);
        }
    }
}

// ---------------- merged QKV projection -> Qf / Kf(scaled) / Vt(transposed) ----------------
__global__ __launch_bounds__(512) void gemm_qkv(const ushort* __restrict__ Xh,
                                                const ushort* __restrict__ Wt,
                                                ushort* __restrict__ Qf,
                                                ushort* __restrict__ Kf,
                                                ushort* __restrict__ Vt) {
    __shared__ ushort sA[256 * 64];
    __shared__ ushort sB[128 * 64];
    const int by0 = blockIdx.y * 256, bx0 = blockIdx.x * 128;
    f32x16 acc[2][2] = {};
    gemm_core(Xh, Wt, (long)by0 * 768, (long)bx0 * 768, sA, sB, acc);

    const int tid = threadIdx.x, lane = tid & 63, w = tid >> 6;
    const int c31 = lane & 31, g1 = lane >> 5;
    const int wr = w >> 1, wc = w & 1;
    const int bb = by0 >> 11, tb = by0 & 2047;     // 256-tiles never cross a batch boundary
#pragma unroll
    for (int nj = 0; nj < 2; ++nj) {
        int n = bx0 + wc * 64 + nj * 32 + c31;
        int gg = n >> 6;                      // 0..11 Q, 12..23 K, 24..35 V
        int d = n & 63;
        if (gg < 24) {
            int kq = gg >= 12;
            int hh = gg - kq * 12;
            ushort* Dst = kq ? Kf : Qf;
            float sc = kq ? 0.1803368801111204f : 1.0f;   // K carries 0.125*log2(e)
            long cb = ((long)(bb * 12 + hh) * 2048) * 64 + d;
#pragma unroll
            for (int mi = 0; mi < 2; ++mi)
#pragma unroll
                for (int r = 0; r < 16; ++r) {
                    int t = tb + wr * 64 + mi * 32 + (r & 3) + 8 * (r >> 2) + 4 * g1;
                    Dst[cb + (long)t * 64] = f2h(acc[mi][nj][r] * sc);
                }
        } else {
            int hh = gg - 24;
            long vb = ((long)(bb * 12 + hh) * 64 + d) * 2048;
#pragma unroll
            for (int mi = 0; mi < 2; ++mi)
#pragma unroll
                for (int rq = 0; rq < 4; ++rq) {
                    int tq = tb + wr * 64 + mi * 32 + 8 * rq + 4 * g1;
                    ushort4v vv;
#pragma unroll
                    for (int j = 0; j < 4; ++j) vv[j] = f2h(acc[mi][nj][4 * rq + j]);
                    *reinterpret_cast<ushort4v*>(&Vt[vb + tq]) = vv;
                }
        }
    }
}

// ---------------- flash attention: 3-slot LDS rotation, unroll-2 ping-pong S regs ----------
__global__ __launch_bounds__(256) void flash_attn(const ushort* __restrict__ Qf,
                                                  const ushort* __restrict__ Kf,
                                                  const ushort* __restrict__ Vt,
                                                  ushort* __restrict__ Of) {
    __shared__ ushort Ks[3][64 * 64];
    __shared__ ushort Vs[3][64 * 64];
    const int tid = threadIdx.x;
    const int w = tid >> 6;
    const int lane = tid & 63;
    const int c = lane & 31, g1 = lane >> 5;
    // XCD-bijective swizzle: all 16 t-blocks of a head land on one XCD.
    const int wgid = blockIdx.x;
    const int xblk = (wgid >> 3) & 15;
    const int bh = (wgid & 7) + 8 * (wgid >> 7);
    const int t0 = xblk * 128 + w * 32;
    const long hb = (long)bh * 2048 * 64;

    // Q frags (single f16; scale folded into K)
    half8 qh[4];
    {
        const long qrow = hb + (long)(t0 + c) * 64;
#pragma unroll
        for (int ks = 0; ks < 4; ++ks)
            qh[ks] = __builtin_bit_cast(half8, *reinterpret_cast<const short8*>(&Qf[qrow + ks * 16 + g1 * 8]));
    }

    // staging geometry (2 rows per thread, 16B each, XOR-swizzled slots)
    const int r0 = tid >> 3, sl = tid & 7, r1 = r0 + 32;
    const int off0 = r0 * 64 + ((sl ^ (r0 & 7)) * 8);
    const int off1 = r1 * 64 + ((sl ^ (r1 & 7)) * 8);

    // prologue: stage tiles 0 and 1 into slots 0 and 1
    {
        short8 k00 = *reinterpret_cast<const short8*>(&Kf[hb + (long)r0 * 64 + sl * 8]);
        short8 k01 = *reinterpret_cast<const short8*>(&Kf[hb + (long)r1 * 64 + sl * 8]);
        short8 v00 = *reinterpret_cast<const short8*>(&Vt[hb + (long)r0 * 2048 + sl * 8]);
        short8 v01 = *reinterpret_cast<const short8*>(&Vt[hb + (long)r1 * 2048 + sl * 8]);
        short8 k10 = *reinterpret_cast<const short8*>(&Kf[hb + (long)(64 + r0) * 64 + sl * 8]);
        short8 k11 = *reinterpret_cast<const short8*>(&Kf[hb + (long)(64 + r1) * 64 + sl * 8]);
        short8 v10 = *reinterpret_cast<const short8*>(&Vt[hb + (long)r0 * 2048 + 64 + sl * 8]);
        short8 v11 = *reinterpret_cast<const short8*>(&Vt[hb + (long)r1 * 2048 + 64 + sl * 8]);
        *reinterpret_cast<short8*>(&Ks[0][off0]) = k00;
        *reinterpret_cast<short8*>(&Ks[0][off1]) = k01;
        *reinterpret_cast<short8*>(&Vs[0][off0]) = v00;
        *reinterpret_cast<short8*>(&Vs[0][off1]) = v01;
        *reinterpret_cast<short8*>(&Ks[1][off0]) = k10;
        *reinterpret_cast<short8*>(&Ks[1][off1]) = k11;
        *reinterpret_cast<short8*>(&Vs[1][off0]) = v10;
        *reinterpret_cast<short8*>(&Vs[1][off1]) = v11;
    }
    __syncthreads();

    // hoisted staging pointers (tile j+2 sources), advanced per iteration
    const ushort* kst0 = &Kf[hb + (long)(128 + r0) * 64 + sl * 8];
    const ushort* kst1 = &Kf[hb + (long)(128 + r1) * 64 + sl * 8];
    const ushort* vst0 = &Vt[hb + (long)r0 * 2048 + 128 + sl * 8];
    const ushort* vst1 = &Vt[hb + (long)r1 * 2048 + 128 + sl * 8];

    const f32x16 kzero = {};

    // S(0) from slot 0
    f32x16 s0, s1;
    {
        half8 k0f = ldfragh(&Ks[0][0], c, g1);
        half8 k1f = ldfragh(&Ks[0][0], 32 + c, g1);
        s0 = mfma16(k0f, qh[0], kzero);
        s1 = mfma16(k1f, qh[0], kzero);
#pragma unroll
        for (int ks = 1; ks < 4; ++ks) {
            int slot = 2 * ks + g1;
            k0f = ldfragh(&Ks[0][0], c, slot);
            k1f = ldfragh(&Ks[0][0], 32 + c, slot);
            s0 = mfma16(k0f, qh[ks], s0);
            s1 = mfma16(k1f, qh[ks], s1);
        }
    }

    f32x16 o0 = {}, o1 = {};
    float lrun = 0.f;
    int p = 0;

    // one attention iteration: consumes cs (S of tile j), produces ns (S of tile j+1)
    auto fiter = [&](bool hasN1, bool hasN2, f32x16& cs0, f32x16& cs1,
                     f32x16& ns0, f32x16& ns1) {
        const int p1 = (p + 1 == 3) ? 0 : p + 1;
        const int p2 = (p + 2 >= 3) ? p + 2 - 3 : p + 2;

        // (1) QK(j+1) MFMAs first — execute in background under softmax(j) VALU
        if (hasN1) {
            __builtin_amdgcn_s_setprio(1);
            half8 k0f = ldfragh(&Ks[p1][0], c, g1);
            half8 k1f = ldfragh(&Ks[p1][0], 32 + c, g1);
            ns0 = mfma16(k0f, qh[0], kzero);
            ns1 = mfma16(k1f, qh[0], kzero);
#pragma unroll
            for (int ks = 1; ks < 4; ++ks) {
                int slot = 2 * ks + g1;
                k0f = ldfragh(&Ks[p1][0], c, slot);
                k1f = ldfragh(&Ks[p1][0], 32 + c, slot);
                ns0 = mfma16(k0f, qh[ks], ns0);
                ns1 = mfma16(k1f, qh[ks], ns1);
            }
            __builtin_amdgcn_s_setprio(0);
        }

        // (2) issue tile(j+2) global loads — latency hidden under softmax+PV
        short8 pk0, pk1, pv0, pv1;
        if (hasN2) {
            pk0 = *reinterpret_cast<const short8*>(kst0);
            pk1 = *reinterpret_cast<const short8*>(kst1);
            pv0 = *reinterpret_cast<const short8*>(vst0);
            pv1 = *reinterpret_cast<const short8*>(vst1);
            kst0 += 4096; kst1 += 4096;
            vst0 += 64;   vst1 += 64;
        }

        // (3) softmax(j): no-max exp2 (scale folded into K)
#pragma unroll
        for (int r = 0; r < 16; ++r) {
            cs0[r] = exp2f(cs0[r]);
            cs1[r] = exp2f(cs1[r]);
        }

        // (4) PV(j): P pack via cvt_pkrtz + permlane32_swap; l via fdot2 on pre-swap pairs
        __builtin_amdgcn_s_setprio(1);
#pragma unroll
        for (int ks = 0; ks < 4; ++ks) {
            const int b8 = (ks & 1) * 8;
            uint4v dv;
#pragma unroll
            for (int mi = 0; mi < 2; ++mi) {
                float aLo = (ks < 2) ? cs0[2 * mi + b8] : cs1[2 * mi + b8];
                float aHi = (ks < 2) ? cs0[2 * mi + b8 + 1] : cs1[2 * mi + b8 + 1];
                float bLo = (ks < 2) ? cs0[2 * mi + b8 + 4] : cs1[2 * mi + b8 + 4];
                float bHi = (ks < 2) ? cs0[2 * mi + b8 + 5] : cs1[2 * mi + b8 + 5];
                unsigned xA = pk2h(aLo, aHi);
                unsigned xB = pk2h(bLo, bHi);
                lrun = dot2acc(xA, lrun);
                lrun = dot2acc(xB, lrun);
                auto rr = __builtin_amdgcn_permlane32_swap(xA, xB, false, false);
                dv[mi] = rr[0];
                dv[2 + mi] = rr[1];
            }
            half8 pb = __builtin_bit_cast(half8, dv);
            int slot = 2 * ks + g1;
            half8 va0 = ldfragh(&Vs[p][0], c, slot);
            half8 va1 = ldfragh(&Vs[p][0], 32 + c, slot);
            o0 = mfma16(va0, pb, o0);
            o1 = mfma16(va1, pb, o1);
        }
        __builtin_amdgcn_s_setprio(0);

        // (5) write tile(j+2) into slot p2
        if (hasN2) {
            *reinterpret_cast<short8*>(&Ks[p2][off0]) = pk0;
            *reinterpret_cast<short8*>(&Ks[p2][off1]) = pk1;
            *reinterpret_cast<short8*>(&Vs[p2][off0]) = pv0;
            *reinterpret_cast<short8*>(&Vs[p2][off1]) = pv1;
        }
        __syncthreads();
        p = p1;
    };

    f32x16 n0, n1;
    for (int j = 0; j < 32; j += 2) {
        fiter(true, j + 2 < 32, s0, s1, n0, n1);          // iteration j   (j<=30 => hasN1)
        fiter(j + 2 < 32, j + 3 < 32, n0, n1, s0, s1);    // iteration j+1
    }

    const float ltot = lrun + __shfl_xor(lrun, 32);
    const float inv = 1.0f / ltot;
    const int bb = bh / 12, h = bh - bb * 12;
    const long obase = ((long)(bb * 2048 + t0 + c)) * 768 + h * 64;
#pragma unroll
    for (int m = 0; m < 4; ++m) {
        int d0 = 8 * m + 4 * g1;
        ushort4v a, b;
#pragma unroll
        for (int j = 0; j < 4; ++j) {
            a[j] = f2h(o0[4 * m + j] * inv);
            b[j] = f2h(o1[4 * m + j] * inv);
        }
        *reinterpret_cast<ushort4v*>(&Of[obase + d0]) = a;
        *reinterpret_cast<ushort4v*>(&Of[obase + 32 + d0]) = b;
    }
}

// ---------------- out projection: 1-term f16 MFMA + bias, fp32 out ----------------
__global__ __launch_bounds__(512) void gemm_out(const ushort* __restrict__ Of,
                                                const ushort* __restrict__ Wo,
                                                const float* __restrict__ bias,
                                                float* __restrict__ Cout) {
    __shared__ ushort sA[256 * 64];
    __shared__ ushort sB[128 * 64];
    const int by0 = blockIdx.y * 256, bx0 = blockIdx.x * 128;
    f32x16 acc[2][2] = {};
    gemm_core(Of, Wo, (long)by0 * 768, (long)bx0 * 768, sA, sB, acc);

    const int tid = threadIdx.x, lane = tid & 63, w = tid >> 6;
    const int c31 = lane & 31, g1 = lane >> 5;
    const int wr = w >> 1, wc = w & 1;
#pragma unroll
    for (int nj = 0; nj < 2; ++nj) {
        int n = bx0 + wc * 64 + nj * 32 + c31;
        float bv = bias[n];
#pragma unroll
        for (int mi = 0; mi < 2; ++mi)
#pragma unroll
            for (int r = 0; r < 16; ++r) {
                int row = by0 + wr * 64 + mi * 32 + (r & 3) + 8 * (r >> 2) + 4 * g1;
                Cout[(long)row * 768 + n] = acc[mi][nj][r] + bv;
            }
    }
}

extern "C" void kernel_launch(void* const* d_in, const int* in_sizes, int n_in,
                              void* d_out, int out_size, void* d_ws, size_t ws_size,
                              hipStream_t stream) {
    const float* x     = (const float*)d_in[0];
    const float* w_qkv = (const float*)d_in[1];
    const float* w_out = (const float*)d_in[2];
    const float* b_out = (const float*)d_in[3];
    float* out = (float*)d_out;

    // ws layout (bytes); U = 48*2048*64*2 = 12,582,912 per f16 tensor
    const long U = 12582912;
    char* p = (char*)d_ws;
    ushort* Xh = (ushort*)(p);                    // later: Of (flash output)
    ushort* Wt = (ushort*)(p + U);                // 3,538,944 B
    ushort* Wo = (ushort*)(p + U + 3538944);      // 1,179,648 B
    ushort* Qf = (ushort*)(p + U + 4718592);
    ushort* Kf = Qf + 6291456;
    ushort* Vt = Kf + 6291456;
    ushort* Of = Xh;

    prep_all  <<<4224, 256, 0, stream>>>(x, w_qkv, w_out, Xh, Wt, Wo);
    gemm_qkv  <<<dim3(18, 32), 512, 0, stream>>>(Xh, Wt, Qf, Kf, Vt);
    flash_attn<<<768, 256, 0, stream>>>(Qf, Kf, Vt, Of);
    gemm_out  <<<dim3(6, 32), 512, 0, stream>>>(Of, Wo, b_out, out);
}

// Round 15
// 191.037 us; speedup vs baseline: 1.0948x; 1.0755x over previous
//
#include <hip/hip_runtime.h>
#include <hip/hip_bf16.h>

// MHA forward. DIM=768, HEADS=12, HD=64, B=4, T=2048.
// All matmuls 1-term f16 MFMA. Flash is KEY-SPLIT x2 (no-max softmax => exact partial
// combine), R12 inner loop, 2-slot K AND V LDS rotation (32KB -> 5 blocks/CU).
//   prep_all -> gemm_qkv(128x128) -> flash_attn(x1536) -> combine(x1536) -> gemm_out(128x128)

typedef short short8 __attribute__((ext_vector_type(8)));
typedef _Float16 half8 __attribute__((ext_vector_type(8)));
typedef _Float16 half2v __attribute__((ext_vector_type(2)));
typedef float f32x16 __attribute__((ext_vector_type(16)));
typedef unsigned int uint4v __attribute__((ext_vector_type(4)));
typedef unsigned short ushort8v __attribute__((ext_vector_type(8)));
typedef unsigned short ushort4v __attribute__((ext_vector_type(4)));
typedef unsigned short ushort;

__device__ __forceinline__ ushort f2h(float x) {
    _Float16 h = (_Float16)x;                      // RNE
    return __builtin_bit_cast(ushort, h);
}
__device__ __forceinline__ float h2f(ushort u) {
    return (float)__builtin_bit_cast(_Float16, u);
}
__device__ __forceinline__ unsigned pk2h(float lo, float hi) {   // packed f16 pair, RTZ
    return __builtin_bit_cast(unsigned, __builtin_amdgcn_cvt_pkrtz(lo, hi));
}
__device__ __forceinline__ float dot2acc(unsigned pair, float acc) {  // acc += lo + hi
    const half2v ones = {(_Float16)1.0f, (_Float16)1.0f};
    return __builtin_amdgcn_fdot2(__builtin_bit_cast(half2v, pair), ones, acc, false);
}
__device__ __forceinline__ short8 ldfrag(const ushort* buf, int row, int slotLogical) {
    int phys = slotLogical ^ (row & 7);
    return *reinterpret_cast<const short8*>(&buf[row * 64 + phys * 8]);
}
__device__ __forceinline__ f32x16 mfma16(half8 a, half8 b, f32x16 c) {
    return __builtin_amdgcn_mfma_f32_32x32x16_f16(a, b, c, 0, 0, 0);
}
__device__ __forceinline__ half8 ldfragh(const ushort* buf, int row, int slotLogical) {
    return __builtin_bit_cast(half8, ldfrag(buf, row, slotLogical));
}
__device__ __forceinline__ void gload16(const ushort* g, ushort* l) {
    __builtin_amdgcn_global_load_lds((__attribute__((address_space(1))) void*)g,
                                     (__attribute__((address_space(3))) void*)l, 16, 0, 0);
}

// ---------------- merged prep: cast x | permute+cast w_qkv | transpose+cast w_out ------------
__global__ __launch_bounds__(256) void prep_all(const float* __restrict__ x,
                                                const float* __restrict__ wqkv,
                                                const float* __restrict__ wout,
                                                ushort* __restrict__ Xh,
                                                ushort* __restrict__ Wt,
                                                ushort* __restrict__ Wo) {
    int b = blockIdx.x;
    if (b < 3072) {
        long i8 = (long)(b * 256 + threadIdx.x) * 8;
        float4 v0 = *reinterpret_cast<const float4*>(&x[i8]);
        float4 v1 = *reinterpret_cast<const float4*>(&x[i8 + 4]);
        float v[8] = {v0.x, v0.y, v0.z, v0.w, v1.x, v1.y, v1.z, v1.w};
        ushort8v hh;
#pragma unroll
        for (int j = 0; j < 8; ++j) hh[j] = f2h(v[j]);
        *reinterpret_cast<ushort8v*>(&Xh[i8]) = hh;
    } else if (b < 3072 + 864) {
        int id = (b - 3072) * 256 + threadIdx.x;  // 2304*96
        int n = id % 2304;
        int oct = id / 2304;
        int g = n >> 6, d = n & 63;
        int col = d * 36 + g;
        ushort8v hh;
#pragma unroll
        for (int i = 0; i < 8; ++i) hh[i] = f2h(wqkv[(long)(8 * oct + i) * 2304 + col]);
        *reinterpret_cast<ushort8v*>(&Wt[(long)n * 768 + 8 * oct]) = hh;
    } else {
        int id = (b - 3936) * 256 + threadIdx.x;  // 768*96
        int n = id % 768;
        int oct = id / 768;
        ushort8v hh;
#pragma unroll
        for (int i = 0; i < 8; ++i) hh[i] = f2h(wout[(long)(8 * oct + i) * 768 + n]);
        *reinterpret_cast<ushort8v*>(&Wo[(long)n * 768 + 8 * oct]) = hh;
    }
}

// ---------------- shared MFMA GEMM core (R12): C[128][128] = A[128][768] . Bt[128][768]^T ----
__device__ __forceinline__ void gemm_core(const ushort* __restrict__ A,
                                          const ushort* __restrict__ Bt,
                                          long aBase, long bBase,
                                          ushort* sA, ushort* sB, f32x16 (&acc)[2][2]) {
    const int tid = threadIdx.x;
    const int lane = tid & 63, w = tid >> 6;
    const int c31 = lane & 31, g1 = lane >> 5;
    const int wr = w >> 1, wc = w & 1;
    const int srow_in_chunk = lane >> 3;
    for (int k0 = 0; k0 < 768; k0 += 64) {
        __syncthreads();
#pragma unroll
        for (int t = 0; t < 4; ++t) {
            int row = w * 32 + t * 8 + srow_in_chunk;
            int sl = (lane & 7) ^ (row & 7);
            long goff = (long)row * 768 + k0 + sl * 8;
            int ldst = (w * 32 + t * 8) * 64;
            gload16(&A[aBase + goff], &sA[ldst]);
            gload16(&Bt[bBase + goff], &sB[ldst]);
        }
        __syncthreads();
#pragma unroll
        for (int ks = 0; ks < 4; ++ks) {
            half8 ah[2], bh[2];
#pragma unroll
            for (int i = 0; i < 2; ++i) {
                ah[i] = ldfragh(sA, wr * 64 + i * 32 + c31, 2 * ks + g1);
                bh[i] = ldfragh(sB, wc * 64 + i * 32 + c31, 2 * ks + g1);
            }
#pragma unroll
            for (int mi = 0; mi < 2; ++mi)
#pragma unroll
                for (int nj = 0; nj < 2; ++nj)
                    acc[mi][nj] = mfma16(ah[mi], bh[nj], acc[mi][nj]);
        }
    }
}

// ---------------- merged QKV projection -> Qf / Kf(scaled) / Vt(transposed) ----------------
__global__ __launch_bounds__(256) void gemm_qkv(const ushort* __restrict__ Xh,
                                                const ushort* __restrict__ Wt,
                                                ushort* __restrict__ Qf,
                                                ushort* __restrict__ Kf,
                                                ushort* __restrict__ Vt) {
    __shared__ ushort sA[128 * 64];
    __shared__ ushort sB[128 * 64];
    const int by0 = blockIdx.y * 128, bx0 = blockIdx.x * 128;
    f32x16 acc[2][2] = {};
    gemm_core(Xh, Wt, (long)by0 * 768, (long)bx0 * 768, sA, sB, acc);

    const int tid = threadIdx.x, lane = tid & 63, w = tid >> 6;
    const int c31 = lane & 31, g1 = lane >> 5;
    const int wr = w >> 1, wc = w & 1;
    const int bb = by0 >> 11, tb = by0 & 2047;
#pragma unroll
    for (int nj = 0; nj < 2; ++nj) {
        int n = bx0 + wc * 64 + nj * 32 + c31;
        int gg = n >> 6;
        int d = n & 63;
        if (gg < 24) {
            int kq = gg >= 12;
            int hh = gg - kq * 12;
            ushort* Dst = kq ? Kf : Qf;
            float sc = kq ? 0.1803368801111204f : 1.0f;   // K carries 0.125*log2(e)
            long cb = ((long)(bb * 12 + hh) * 2048) * 64 + d;
#pragma unroll
            for (int mi = 0; mi < 2; ++mi)
#pragma unroll
                for (int r = 0; r < 16; ++r) {
                    int t = tb + wr * 64 + mi * 32 + (r & 3) + 8 * (r >> 2) + 4 * g1;
                    Dst[cb + (long)t * 64] = f2h(acc[mi][nj][r] * sc);
                }
        } else {
            int hh = gg - 24;
            long vb = ((long)(bb * 12 + hh) * 64 + d) * 2048;
#pragma unroll
            for (int mi = 0; mi < 2; ++mi)
#pragma unroll
                for (int rq = 0; rq < 4; ++rq) {
                    int tq = tb + wr * 64 + mi * 32 + 8 * rq + 4 * g1;
                    ushort4v vv;
#pragma unroll
                    for (int j = 0; j < 4; ++j) vv[j] = f2h(acc[mi][nj][4 * rq + j]);
                    *reinterpret_cast<ushort4v*>(&Vt[vb + tq]) = vv;
                }
        }
    }
}

// ---------------- flash attention, key-split x2: 128 q x 1024 keys per block ----------------
// R12 inner loop; 2-slot K and V (parity rotation, 32KB LDS -> 5 blocks/CU).
// At iter j: QK-ahead reads Ks[(j+1)&1]; PV reads Vs[j&1];
//            writes K tile j+2 -> Ks[j&1], V tile j+1 -> Vs[(j+1)&1] (barrier-separated).
__global__ __launch_bounds__(256) void flash_attn(const ushort* __restrict__ Qf,
                                                  const ushort* __restrict__ Kf,
                                                  const ushort* __restrict__ Vt,
                                                  ushort* __restrict__ Op0,
                                                  ushort* __restrict__ Op1,
                                                  float* __restrict__ lp0,
                                                  float* __restrict__ lp1) {
    __shared__ ushort Ks[2][64 * 64];
    __shared__ ushort Vs[2][64 * 64];
    const int tid = threadIdx.x;
    const int w = tid >> 6;
    const int lane = tid & 63;
    const int c = lane & 31, g1 = lane >> 5;
    // swizzle: wgid&7 = bh&7 (XCD-local); inner: xblk(16) x kh(2); bh = (wgid&7)+8*(wgid>>8)
    const int wgid = blockIdx.x;
    const int inner = (wgid >> 3) & 31;
    const int xblk = inner >> 1;
    const int kh = inner & 1;
    const int bh = (wgid & 7) + 8 * (wgid >> 8);
    const int t0 = xblk * 128 + w * 32;
    const long hb = (long)bh * 2048 * 64;
    const int jbase = kh * 1024;

    // Q frags (single f16; scale folded into K)
    half8 qh[4];
    {
        const long qrow = hb + (long)(t0 + c) * 64;
#pragma unroll
        for (int ks = 0; ks < 4; ++ks)
            qh[ks] = __builtin_bit_cast(half8, *reinterpret_cast<const short8*>(&Qf[qrow + ks * 16 + g1 * 8]));
    }

    // staging geometry (2 rows per thread, 16B each, XOR-swizzled slots)
    const int r0 = tid >> 3, sl = tid & 7, r1 = r0 + 32;
    const int off0 = r0 * 64 + ((sl ^ (r0 & 7)) * 8);
    const int off1 = r1 * 64 + ((sl ^ (r1 & 7)) * 8);

    // prologue: K tiles 0,1 -> Ks[0],Ks[1]; V tile 0 -> Vs[0]
    {
        short8 k00 = *reinterpret_cast<const short8*>(&Kf[hb + (long)(jbase + r0) * 64 + sl * 8]);
        short8 k01 = *reinterpret_cast<const short8*>(&Kf[hb + (long)(jbase + r1) * 64 + sl * 8]);
        short8 k10 = *reinterpret_cast<const short8*>(&Kf[hb + (long)(jbase + 64 + r0) * 64 + sl * 8]);
        short8 k11 = *reinterpret_cast<const short8*>(&Kf[hb + (long)(jbase + 64 + r1) * 64 + sl * 8]);
        short8 v00 = *reinterpret_cast<const short8*>(&Vt[hb + (long)r0 * 2048 + jbase + sl * 8]);
        short8 v01 = *reinterpret_cast<const short8*>(&Vt[hb + (long)r1 * 2048 + jbase + sl * 8]);
        *reinterpret_cast<short8*>(&Ks[0][off0]) = k00;
        *reinterpret_cast<short8*>(&Ks[0][off1]) = k01;
        *reinterpret_cast<short8*>(&Ks[1][off0]) = k10;
        *reinterpret_cast<short8*>(&Ks[1][off1]) = k11;
        *reinterpret_cast<short8*>(&Vs[0][off0]) = v00;
        *reinterpret_cast<short8*>(&Vs[0][off1]) = v01;
    }
    __syncthreads();

    // hoisted staging pointers: K at tile j+2 (starts tile 2), V at tile j+1 (starts tile 1)
    const ushort* kst0 = &Kf[hb + (long)(jbase + 128 + r0) * 64 + sl * 8];
    const ushort* kst1 = &Kf[hb + (long)(jbase + 128 + r1) * 64 + sl * 8];
    const ushort* vst0 = &Vt[hb + (long)r0 * 2048 + jbase + 64 + sl * 8];
    const ushort* vst1 = &Vt[hb + (long)r1 * 2048 + jbase + 64 + sl * 8];

    // S(0) from Ks[0]
    f32x16 s0 = {}, s1 = {};
#pragma unroll
    for (int ks = 0; ks < 4; ++ks) {
        int slot = 2 * ks + g1;
        half8 k0f = ldfragh(&Ks[0][0], c, slot);
        half8 k1f = ldfragh(&Ks[0][0], 32 + c, slot);
        s0 = mfma16(k0f, qh[ks], s0);
        s1 = mfma16(k1f, qh[ks], s1);
    }

    f32x16 o0 = {}, o1 = {};
    float lrun = 0.f;

    for (int j = 0; j < 16; ++j) {
        const int par = j & 1;
        const bool hasN1 = j + 1 < 16;   // QK-ahead + V-load guard
        const bool hasN2 = j + 2 < 16;   // K-load guard

        // (1) QK(j+1) MFMAs first — execute in background under softmax(j) VALU
        f32x16 n0 = {}, n1 = {};
        if (hasN1) {
            __builtin_amdgcn_s_setprio(1);
#pragma unroll
            for (int ks = 0; ks < 4; ++ks) {
                int slot = 2 * ks + g1;
                half8 k0f = ldfragh(&Ks[par ^ 1][0], c, slot);
                half8 k1f = ldfragh(&Ks[par ^ 1][0], 32 + c, slot);
                n0 = mfma16(k0f, qh[ks], n0);
                n1 = mfma16(k1f, qh[ks], n1);
            }
            __builtin_amdgcn_s_setprio(0);
        }

        // (2) issue K(j+2), V(j+1) global loads — latency hidden under softmax+PV
        short8 pk0, pk1, pv0, pv1;
        if (hasN2) {
            pk0 = *reinterpret_cast<const short8*>(kst0);
            pk1 = *reinterpret_cast<const short8*>(kst1);
            kst0 += 4096; kst1 += 4096;
        }
        if (hasN1) {
            pv0 = *reinterpret_cast<const short8*>(vst0);
            pv1 = *reinterpret_cast<const short8*>(vst1);
            vst0 += 64; vst1 += 64;
        }

        // (3) softmax(j): no-max exp2 (scale folded into K)
#pragma unroll
        for (int r = 0; r < 16; ++r) {
            s0[r] = exp2f(s0[r]);
            s1[r] = exp2f(s1[r]);
        }

        // (4) PV(j): P pack via cvt_pkrtz + permlane32_swap; l via fdot2 on pre-swap pairs
        __builtin_amdgcn_s_setprio(1);
#pragma unroll
        for (int ks = 0; ks < 4; ++ks) {
            const int b8 = (ks & 1) * 8;
            uint4v dv;
#pragma unroll
            for (int mi = 0; mi < 2; ++mi) {
                float aLo = (ks < 2) ? s0[2 * mi + b8] : s1[2 * mi + b8];
                float aHi = (ks < 2) ? s0[2 * mi + b8 + 1] : s1[2 * mi + b8 + 1];
                float bLo = (ks < 2) ? s0[2 * mi + b8 + 4] : s1[2 * mi + b8 + 4];
                float bHi = (ks < 2) ? s0[2 * mi + b8 + 5] : s1[2 * mi + b8 + 5];
                unsigned xA = pk2h(aLo, aHi);
                unsigned xB = pk2h(bLo, bHi);
                lrun = dot2acc(xA, lrun);
                lrun = dot2acc(xB, lrun);
                auto rr = __builtin_amdgcn_permlane32_swap(xA, xB, false, false);
                dv[mi] = rr[0];
                dv[2 + mi] = rr[1];
            }
            half8 pb = __builtin_bit_cast(half8, dv);
            int slot = 2 * ks + g1;
            half8 va0 = ldfragh(&Vs[par][0], c, slot);
            half8 va1 = ldfragh(&Vs[par][0], 32 + c, slot);
            o0 = mfma16(va0, pb, o0);
            o1 = mfma16(va1, pb, o1);
        }
        __builtin_amdgcn_s_setprio(0);

        // (5) write K(j+2) -> Ks[par], V(j+1) -> Vs[par^1]
        if (hasN2) {
            *reinterpret_cast<short8*>(&Ks[par][off0]) = pk0;
            *reinterpret_cast<short8*>(&Ks[par][off1]) = pk1;
        }
        if (hasN1) {
            *reinterpret_cast<short8*>(&Vs[par ^ 1][off0]) = pv0;
            *reinterpret_cast<short8*>(&Vs[par ^ 1][off1]) = pv1;
        }
        __syncthreads();

        s0 = n0; s1 = n1;
    }

    const float ltot = lrun + __shfl_xor(lrun, 32);
    // partial stores: Op[kh][(bh*64 + d)*2048 + q] f16 (coalesced along q), l f32
    ushort* Op = kh ? Op1 : Op0;
    float* lp = kh ? lp1 : lp0;
    const long pbase = ((long)bh * 64) * 2048 + t0 + c;
#pragma unroll
    for (int r = 0; r < 16; ++r) {
        int d0 = (r & 3) + 8 * (r >> 2) + 4 * g1;
        Op[pbase + (long)d0 * 2048] = f2h(o0[r]);
        Op[pbase + (long)(32 + d0) * 2048] = f2h(o1[r]);
    }
    if (g1 == 0) lp[(long)bh * 2048 + t0 + c] = ltot;
}

// ---------------- combine: Of[b][t][h*64+d] = (O0+O1)/(l0+l1), LDS 64x64 transpose ----------
__global__ __launch_bounds__(256) void combine(const ushort* __restrict__ Op0,
                                               const ushort* __restrict__ Op1,
                                               const float* __restrict__ lp0,
                                               const float* __restrict__ lp1,
                                               ushort* __restrict__ Of) {
    __shared__ float linv[64];
    __shared__ ushort tile[64][72];           // [t][d], padded
    const int bh = blockIdx.x >> 5;
    const int tb = blockIdx.x & 31;
    const int t0 = tb * 64;
    const int tid = threadIdx.x;
    if (tid < 64)
        linv[tid] = 1.0f / (lp0[(long)bh * 2048 + t0 + tid] + lp1[(long)bh * 2048 + t0 + tid]);
    __syncthreads();
#pragma unroll
    for (int it = 0; it < 2; ++it) {          // 512 tasks: (d 64) x (tg 8)
        int u = tid + 256 * it;
        int d = u & 63, tg = u >> 6;
        long base = ((long)bh * 64 + d) * 2048 + t0 + tg * 8;
        ushort8v a = *reinterpret_cast<const ushort8v*>(&Op0[base]);
        ushort8v b = *reinterpret_cast<const ushort8v*>(&Op1[base]);
#pragma unroll
        for (int j = 0; j < 8; ++j)
            tile[tg * 8 + j][d] = f2h((h2f(a[j]) + h2f(b[j])) * linv[tg * 8 + j]);
    }
    __syncthreads();
    const int bb = bh / 12, h = bh - bb * 12;
#pragma unroll
    for (int it = 0; it < 2; ++it) {          // 512 tasks: (t 64) x (dg 8)
        int u = tid + 256 * it;
        int dg = u & 7, t = u >> 3;
        ushort8v v;
#pragma unroll
        for (int j = 0; j < 8; ++j) v[j] = tile[t][dg * 8 + j];
        *reinterpret_cast<ushort8v*>(&Of[((long)(bb * 2048) + t0 + t) * 768 + h * 64 + dg * 8]) = v;
    }
}

// ---------------- out projection: 1-term f16 MFMA + bias, fp32 out ----------------
__global__ __launch_bounds__(256) void gemm_out(const ushort* __restrict__ Of,
                                                const ushort* __restrict__ Wo,
                                                const float* __restrict__ bias,
                                                float* __restrict__ Cout) {
    __shared__ ushort sA[128 * 64];
    __shared__ ushort sB[128 * 64];
    const int by0 = blockIdx.y * 128, bx0 = blockIdx.x * 128;
    f32x16 acc[2][2] = {};
    gemm_core(Of, Wo, (long)by0 * 768, (long)bx0 * 768, sA, sB, acc);

    const int tid = threadIdx.x, lane = tid & 63, w = tid >> 6;
    const int c31 = lane & 31, g1 = lane >> 5;
    const int wr = w >> 1, wc = w & 1;
#pragma unroll
    for (int nj = 0; nj < 2; ++nj) {
        int n = bx0 + wc * 64 + nj * 32 + c31;
        float bv = bias[n];
#pragma unroll
        for (int mi = 0; mi < 2; ++mi)
#pragma unroll
            for (int r = 0; r < 16; ++r) {
                int row = by0 + wr * 64 + mi * 32 + (r & 3) + 8 * (r >> 2) + 4 * g1;
                Cout[(long)row * 768 + n] = acc[mi][nj][r] + bv;
            }
    }
}

extern "C" void kernel_launch(void* const* d_in, const int* in_sizes, int n_in,
                              void* d_out, int out_size, void* d_ws, size_t ws_size,
                              hipStream_t stream) {
    const float* x     = (const float*)d_in[0];
    const float* w_qkv = (const float*)d_in[1];
    const float* w_out = (const float*)d_in[2];
    const float* b_out = (const float*)d_in[3];
    float* out = (float*)d_out;

    // ws layout (bytes); U = 48*2048*64*2 = 12,582,912 per f16 tensor
    const long U = 12582912;
    char* p = (char*)d_ws;
    ushort* Xh  = (ushort*)(p);                   // later: Of (combined flash output)
    ushort* Wt  = (ushort*)(p + U);               // 3,538,944 B
    ushort* Wo  = (ushort*)(p + U + 3538944);     // 1,179,648 B
    ushort* Qf  = (ushort*)(p + U + 4718592);
    ushort* Kf  = Qf + 6291456;
    ushort* Vt  = Kf + 6291456;
    ushort* Op0 = Vt + 6291456;
    ushort* Op1 = Op0 + 6291456;
    float*  lp0 = (float*)(Op1 + 6291456);        // 393,216 B each
    float*  lp1 = lp0 + 98304;
    ushort* Of  = Xh;

    prep_all  <<<4224, 256, 0, stream>>>(x, w_qkv, w_out, Xh, Wt, Wo);
    gemm_qkv  <<<dim3(18, 64), 256, 0, stream>>>(Xh, Wt, Qf, Kf, Vt);
    flash_attn<<<1536, 256, 0, stream>>>(Qf, Kf, Vt, Op0, Op1, lp0, lp1);
    combine   <<<1536, 256, 0, stream>>>(Op0, Op1, lp0, lp1, Of);
    gemm_out  <<<dim3(6, 64), 256, 0, stream>>>(Of, Wo, b_out, out);
}